// Round 1
// baseline (551.470 us; speedup 1.0000x reference)
//
#include <hip/hip_runtime.h>
#include <cfloat>
#include <cmath>

#define LN_EPS 1e-5f

constexpr int L   = 200;  // sequence length
constexpr int D   = 128;  // embedding dim
constexpr int LPW = 50;   // positions per wave (4 waves)
constexpr int ITER = 25;  // 2 positions per iteration (two 32-lane halves)

__global__ __launch_bounds__(256)
void fue_kernel(const float* __restrict__ emb,
                const int*   __restrict__ lengths,
                const float* __restrict__ w_att,
                const float* __restrict__ b_att,
                const float* __restrict__ gamma,
                const float* __restrict__ beta,
                float* __restrict__ out) {
    const int b    = blockIdx.x;
    const int tid  = threadIdx.x;
    const int wave = tid >> 6;
    const int lane = tid & 63;
    const int half = lane >> 5;   // which of the two 32-lane halves
    const int hl   = lane & 31;   // lane within half

    __shared__ float sc[L];        // scores -> exp values
    __shared__ float red[16];      // cross-wave reduction scratch
    __shared__ float partial[4][D];

    const int   len  = lengths[b];
    const float bias = b_att[0];

    // each half-lane owns dims [4*hl, 4*hl+4)
    const float4 wv = ((const float4*)w_att)[hl];

    const float* row = emb + (size_t)b * (L * D);

    float4 cache[ITER];

    // ---- Pass 1: attention scores (single HBM read, cached in VGPRs) ----
    #pragma unroll
    for (int j = 0; j < ITER; ++j) {
        const int l = wave * LPW + 2 * j + half;
        const float4 x = *(const float4*)(row + l * D + hl * 4);
        cache[j] = x;
        float s = x.x * wv.x + x.y * wv.y + x.z * wv.z + x.w * wv.w;
        // reduce across the 32 lanes of this half
        s += __shfl_xor(s, 1);
        s += __shfl_xor(s, 2);
        s += __shfl_xor(s, 4);
        s += __shfl_xor(s, 8);
        s += __shfl_xor(s, 16);
        if (hl == 0)
            sc[l] = (l < len) ? (s + bias) : -FLT_MAX;
    }
    __syncthreads();

    // ---- Softmax over sc[0..L) ----
    float v = (tid < L) ? sc[tid] : -FLT_MAX;
    float m = v;
    m = fmaxf(m, __shfl_xor(m, 1));
    m = fmaxf(m, __shfl_xor(m, 2));
    m = fmaxf(m, __shfl_xor(m, 4));
    m = fmaxf(m, __shfl_xor(m, 8));
    m = fmaxf(m, __shfl_xor(m, 16));
    m = fmaxf(m, __shfl_xor(m, 32));
    if (lane == 0) red[wave] = m;
    __syncthreads();
    m = fmaxf(fmaxf(red[0], red[1]), fmaxf(red[2], red[3]));

    float e = (tid < L) ? __expf(v - m) : 0.0f;
    if (tid < L) sc[tid] = e;   // safe: next read of sc is after the barrier below
    float s = e;
    s += __shfl_xor(s, 1);
    s += __shfl_xor(s, 2);
    s += __shfl_xor(s, 4);
    s += __shfl_xor(s, 8);
    s += __shfl_xor(s, 16);
    s += __shfl_xor(s, 32);
    if (lane == 0) red[4 + wave] = s;
    __syncthreads();
    const float inv = 1.0f / (red[4] + red[5] + red[6] + red[7]);

    // ---- Pass 2: attention-weighted pooling from register cache ----
    float4 acc = make_float4(0.f, 0.f, 0.f, 0.f);
    #pragma unroll
    for (int j = 0; j < ITER; ++j) {
        const int l = wave * LPW + 2 * j + half;
        const float a = sc[l] * inv;   // LDS broadcast within half-wave
        acc.x += a * cache[j].x;
        acc.y += a * cache[j].y;
        acc.z += a * cache[j].z;
        acc.w += a * cache[j].w;
    }
    // fold the two halves together (they cover the same dims for different l)
    acc.x += __shfl_xor(acc.x, 32);
    acc.y += __shfl_xor(acc.y, 32);
    acc.z += __shfl_xor(acc.z, 32);
    acc.w += __shfl_xor(acc.w, 32);
    if (half == 0)
        *(float4*)&partial[wave][hl * 4] = acc;
    __syncthreads();

    // ---- pooled + LayerNorm over D=128 (waves 0,1) ----
    float p = 0.f;
    if (tid < D)
        p = partial[0][tid] + partial[1][tid] + partial[2][tid] + partial[3][tid];

    float s1 = p, s2 = p * p;
    s1 += __shfl_xor(s1, 1);  s2 += __shfl_xor(s2, 1);
    s1 += __shfl_xor(s1, 2);  s2 += __shfl_xor(s2, 2);
    s1 += __shfl_xor(s1, 4);  s2 += __shfl_xor(s2, 4);
    s1 += __shfl_xor(s1, 8);  s2 += __shfl_xor(s2, 8);
    s1 += __shfl_xor(s1, 16); s2 += __shfl_xor(s2, 16);
    s1 += __shfl_xor(s1, 32); s2 += __shfl_xor(s2, 32);
    if (lane == 0 && wave < 2) { red[8 + wave] = s1; red[10 + wave] = s2; }
    __syncthreads();

    const float sum1 = red[8] + red[9];
    const float sum2 = red[10] + red[11];
    const float mu   = sum1 * (1.0f / D);
    const float var  = sum2 * (1.0f / D) - mu * mu;
    const float rstd = rsqrtf(var + LN_EPS);

    if (tid < D)
        out[(size_t)b * D + tid] = (p - mu) * rstd * gamma[tid] + beta[tid];
}

extern "C" void kernel_launch(void* const* d_in, const int* in_sizes, int n_in,
                              void* d_out, int out_size, void* d_ws, size_t ws_size,
                              hipStream_t stream) {
    const float* emb     = (const float*)d_in[0];
    const int*   lengths = (const int*)d_in[1];
    const float* w_att   = (const float*)d_in[2];
    const float* b_att   = (const float*)d_in[3];
    const float* gamma   = (const float*)d_in[4];
    const float* beta    = (const float*)d_in[5];
    float* out = (float*)d_out;

    const int B = in_sizes[1];
    fue_kernel<<<B, 256, 0, stream>>>(emb, lengths, w_att, b_att, gamma, beta, out);
}

// Round 2
// 514.015 us; speedup vs baseline: 1.0729x; 1.0729x over previous
//
#include <hip/hip_runtime.h>
#include <cfloat>
#include <cmath>

#define LN_EPS 1e-5f

constexpr int L = 200;   // max sequence length
constexpr int D = 128;   // embedding dim

__global__ __launch_bounds__(512, 4)
void fue_kernel(const float* __restrict__ emb,
                const int*   __restrict__ lengths,
                const float* __restrict__ w_att,
                const float* __restrict__ b_att,
                const float* __restrict__ gamma,
                const float* __restrict__ beta,
                float* __restrict__ out) {
    const int b    = blockIdx.x;
    const int tid  = threadIdx.x;
    const int wave = tid >> 6;
    const int lane = tid & 63;
    const int hw   = tid >> 5;   // half-wave id, 0..15
    const int hl   = tid & 31;   // lane in half-wave

    __shared__ __align__(16) unsigned short row16[L * D]; // bf16 row cache (51.2 KB)
    __shared__ float att[L];                              // scores -> exp values
    __shared__ float partial[16][D];                      // pooling partials (8 KB)
    __shared__ float red[16];                             // cross-wave scratch

    const int   len  = lengths[b];            // 1 <= len < 200
    const float bias = b_att[0];
    const float4 wv  = ((const float4*)w_att)[hl];
    const float* row = emb + (size_t)b * (L * D);

    const int iters = (len + 15) >> 4;        // uniform across block

    // ---- Pass 1 (fused): load only l < len, score, stash bf16 in LDS ----
    for (int i = 0; i < iters; ++i) {
        const int l = hw + (i << 4);          // uniform within half-wave
        if (l < len) {
            const float4 x = *(const float4*)(row + l * D + hl * 4);

            // fp32 -> bf16 round-to-nearest-even, pack 4 into uint2
            unsigned bx = __float_as_uint(x.x), by = __float_as_uint(x.y);
            unsigned bz = __float_as_uint(x.z), bw = __float_as_uint(x.w);
            bx = (bx + 0x7fffu + ((bx >> 16) & 1u)) >> 16;
            by = (by + 0x7fffu + ((by >> 16) & 1u)) >> 16;
            bz = (bz + 0x7fffu + ((bz >> 16) & 1u)) >> 16;
            bw = (bw + 0x7fffu + ((bw >> 16) & 1u)) >> 16;
            uint2 pk = make_uint2(bx | (by << 16), bz | (bw << 16));
            *(uint2*)&row16[l * D + hl * 4] = pk;

            float s = x.x * wv.x + x.y * wv.y + x.z * wv.z + x.w * wv.w;
            s += __shfl_xor(s, 1);
            s += __shfl_xor(s, 2);
            s += __shfl_xor(s, 4);
            s += __shfl_xor(s, 8);
            s += __shfl_xor(s, 16);
            if (hl == 0) att[l] = s + bias;
        }
    }
    __syncthreads();

    // ---- Softmax over att[0..len) across 8 waves ----
    float v = (tid < len) ? att[tid] : -FLT_MAX;
    float m = v;
    m = fmaxf(m, __shfl_xor(m, 1));
    m = fmaxf(m, __shfl_xor(m, 2));
    m = fmaxf(m, __shfl_xor(m, 4));
    m = fmaxf(m, __shfl_xor(m, 8));
    m = fmaxf(m, __shfl_xor(m, 16));
    m = fmaxf(m, __shfl_xor(m, 32));
    if (lane == 0) red[wave] = m;
    __syncthreads();
    m = red[0];
    #pragma unroll
    for (int k = 1; k < 8; ++k) m = fmaxf(m, red[k]);

    const float e = (tid < len) ? __expf(v - m) : 0.0f;
    if (tid < L) att[tid] = e;   // read of att[tid] happened before prior barrier

    float s = e;
    s += __shfl_xor(s, 1);
    s += __shfl_xor(s, 2);
    s += __shfl_xor(s, 4);
    s += __shfl_xor(s, 8);
    s += __shfl_xor(s, 16);
    s += __shfl_xor(s, 32);
    if (lane == 0) red[8 + wave] = s;
    __syncthreads();
    float tot = red[8];
    #pragma unroll
    for (int k = 1; k < 8; ++k) tot += red[8 + k];
    const float inv = 1.0f / tot;

    // ---- Pass 2: attention-weighted pooling from bf16 LDS ----
    float4 acc = make_float4(0.f, 0.f, 0.f, 0.f);
    for (int i = 0; i < iters; ++i) {
        const int l = hw + (i << 4);
        if (l < len) {
            const float a = att[l] * inv;      // LDS broadcast
            const uint2 pk = *(const uint2*)&row16[l * D + hl * 4];
            const float x0 = __uint_as_float(pk.x << 16);
            const float x1 = __uint_as_float(pk.x & 0xffff0000u);
            const float x2 = __uint_as_float(pk.y << 16);
            const float x3 = __uint_as_float(pk.y & 0xffff0000u);
            acc.x += a * x0;
            acc.y += a * x1;
            acc.z += a * x2;
            acc.w += a * x3;
        }
    }
    *(float4*)&partial[hw][hl * 4] = acc;      // zero if no iterations ran
    __syncthreads();

    // ---- Combine 16 partials + LayerNorm over D=128 (waves 0,1) ----
    float p = 0.f;
    if (tid < D) {
        #pragma unroll
        for (int g = 0; g < 16; ++g) p += partial[g][tid];
    }
    float s1 = p, s2 = p * p;
    s1 += __shfl_xor(s1, 1);  s2 += __shfl_xor(s2, 1);
    s1 += __shfl_xor(s1, 2);  s2 += __shfl_xor(s2, 2);
    s1 += __shfl_xor(s1, 4);  s2 += __shfl_xor(s2, 4);
    s1 += __shfl_xor(s1, 8);  s2 += __shfl_xor(s2, 8);
    s1 += __shfl_xor(s1, 16); s2 += __shfl_xor(s2, 16);
    s1 += __shfl_xor(s1, 32); s2 += __shfl_xor(s2, 32);
    if (lane == 0 && wave < 2) { red[wave] = s1; red[2 + wave] = s2; }
    __syncthreads();

    if (tid < D) {
        const float mu   = (red[0] + red[1]) * (1.0f / D);
        const float var  = (red[2] + red[3]) * (1.0f / D) - mu * mu;
        const float rstd = rsqrtf(var + LN_EPS);
        out[(size_t)b * D + tid] = (p - mu) * rstd * gamma[tid] + beta[tid];
    }
}

extern "C" void kernel_launch(void* const* d_in, const int* in_sizes, int n_in,
                              void* d_out, int out_size, void* d_ws, size_t ws_size,
                              hipStream_t stream) {
    const float* emb     = (const float*)d_in[0];
    const int*   lengths = (const int*)d_in[1];
    const float* w_att   = (const float*)d_in[2];
    const float* b_att   = (const float*)d_in[3];
    const float* gamma   = (const float*)d_in[4];
    const float* beta    = (const float*)d_in[5];
    float* out = (float*)d_out;

    const int B = in_sizes[1];
    fue_kernel<<<B, 512, 0, stream>>>(emb, lengths, w_att, b_att, gamma, beta, out);
}

// Round 3
// 506.733 us; speedup vs baseline: 1.0883x; 1.0144x over previous
//
#include <hip/hip_runtime.h>
#include <cfloat>
#include <cmath>

#define LN_EPS 1e-5f

constexpr int L    = 200;  // max sequence length
constexpr int D    = 128;  // embedding dim
constexpr int JMAX = 13;   // ceil(199/16) positions per half-wave

__global__ __launch_bounds__(512, 4)
void fue_kernel(const float* __restrict__ emb,
                const int*   __restrict__ lengths,
                const float* __restrict__ w_att,
                const float* __restrict__ b_att,
                const float* __restrict__ gamma,
                const float* __restrict__ beta,
                float* __restrict__ out) {
    const int b    = blockIdx.x;
    const int tid  = threadIdx.x;
    const int wave = tid >> 6;
    const int lane = tid & 63;
    const int hw   = tid >> 5;   // half-wave id, 0..15
    const int hl   = tid & 31;   // lane in half-wave

    __shared__ float att[L];           // scores -> exp values
    __shared__ float partial[16][D];   // pooling partials (8 KB)
    __shared__ float red[16];          // cross-wave scratch

    const int   len  = lengths[b];     // 1 <= len <= 199
    const float bias = b_att[0];
    const float4 wv  = ((const float4*)w_att)[hl];
    const float* row = emb + (size_t)b * (L * D);

    // ---- Phase A: issue ALL loads back-to-back (13 KB in flight / wave) ----
    float4 x[JMAX];
    #pragma unroll
    for (int j = 0; j < JMAX; ++j) {
        const int l = hw + (j << 4);
        if (l < len)
            x[j] = *(const float4*)(row + l * D + hl * 4);
    }

    // ---- Phase B: attention scores (independent shuffle chains) ----
    #pragma unroll
    for (int j = 0; j < JMAX; ++j) {
        const int l = hw + (j << 4);
        if (l < len) {
            float s = x[j].x * wv.x + x[j].y * wv.y + x[j].z * wv.z + x[j].w * wv.w;
            s += __shfl_xor(s, 1);
            s += __shfl_xor(s, 2);
            s += __shfl_xor(s, 4);
            s += __shfl_xor(s, 8);
            s += __shfl_xor(s, 16);
            if (hl == 0) att[l] = s + bias;
        }
    }
    __syncthreads();

    // ---- Softmax over att[0..len) across 8 waves ----
    float v = (tid < len) ? att[tid] : -FLT_MAX;
    float m = v;
    m = fmaxf(m, __shfl_xor(m, 1));
    m = fmaxf(m, __shfl_xor(m, 2));
    m = fmaxf(m, __shfl_xor(m, 4));
    m = fmaxf(m, __shfl_xor(m, 8));
    m = fmaxf(m, __shfl_xor(m, 16));
    m = fmaxf(m, __shfl_xor(m, 32));
    if (lane == 0) red[wave] = m;
    __syncthreads();
    m = red[0];
    #pragma unroll
    for (int k = 1; k < 8; ++k) m = fmaxf(m, red[k]);

    const float e = (tid < len) ? __expf(v - m) : 0.0f;
    if (tid < L) att[tid] = e;   // own-slot write; no cross-thread hazard

    float s = e;
    s += __shfl_xor(s, 1);
    s += __shfl_xor(s, 2);
    s += __shfl_xor(s, 4);
    s += __shfl_xor(s, 8);
    s += __shfl_xor(s, 16);
    s += __shfl_xor(s, 32);
    if (lane == 0) red[8 + wave] = s;
    __syncthreads();
    float tot = red[8];
    #pragma unroll
    for (int k = 1; k < 8; ++k) tot += red[8 + k];
    const float inv = 1.0f / tot;

    // ---- Pass 2: attention-weighted pooling from the REGISTER cache ----
    float4 acc = make_float4(0.f, 0.f, 0.f, 0.f);
    #pragma unroll
    for (int j = 0; j < JMAX; ++j) {
        const int l = hw + (j << 4);
        if (l < len) {
            const float a = att[l] * inv;   // LDS broadcast within half-wave
            acc.x += a * x[j].x;
            acc.y += a * x[j].y;
            acc.z += a * x[j].z;
            acc.w += a * x[j].w;
        }
    }
    *(float4*)&partial[hw][hl * 4] = acc;
    __syncthreads();

    // ---- Combine 16 partials + LayerNorm over D=128 ----
    float p = 0.f;
    if (tid < D) {
        #pragma unroll
        for (int g = 0; g < 16; ++g) p += partial[g][tid];
    }
    float s1 = p, s2 = p * p;
    s1 += __shfl_xor(s1, 1);  s2 += __shfl_xor(s2, 1);
    s1 += __shfl_xor(s1, 2);  s2 += __shfl_xor(s2, 2);
    s1 += __shfl_xor(s1, 4);  s2 += __shfl_xor(s2, 4);
    s1 += __shfl_xor(s1, 8);  s2 += __shfl_xor(s2, 8);
    s1 += __shfl_xor(s1, 16); s2 += __shfl_xor(s2, 16);
    s1 += __shfl_xor(s1, 32); s2 += __shfl_xor(s2, 32);
    if (lane == 0 && wave < 2) { red[wave] = s1; red[2 + wave] = s2; }
    __syncthreads();

    if (tid < D) {
        const float mu   = (red[0] + red[1]) * (1.0f / D);
        const float var  = (red[2] + red[3]) * (1.0f / D) - mu * mu;
        const float rstd = rsqrtf(var + LN_EPS);
        out[(size_t)b * D + tid] = (p - mu) * rstd * gamma[tid] + beta[tid];
    }
}

extern "C" void kernel_launch(void* const* d_in, const int* in_sizes, int n_in,
                              void* d_out, int out_size, void* d_ws, size_t ws_size,
                              hipStream_t stream) {
    const float* emb     = (const float*)d_in[0];
    const int*   lengths = (const int*)d_in[1];
    const float* w_att   = (const float*)d_in[2];
    const float* b_att   = (const float*)d_in[3];
    const float* gamma   = (const float*)d_in[4];
    const float* beta    = (const float*)d_in[5];
    float* out = (float*)d_out;

    const int B = in_sizes[1];
    fue_kernel<<<B, 512, 0, stream>>>(emb, lengths, w_att, b_att, gamma, beta, out);
}